// Round 12
// baseline (80.057 us; speedup 1.0000x reference)
//
#include <hip/hip_runtime.h>

typedef __bf16 bf16x8 __attribute__((ext_vector_type(8)));
typedef float f32x16 __attribute__((ext_vector_type(16)));

static __device__ __forceinline__ f32x16 mfma32(bf16x8 a, bf16x8 b, f32x16 c) {
  return __builtin_amdgcn_mfma_f32_32x32x16_bf16(a, b, c, 0, 0, 0);
}
static __device__ __forceinline__ unsigned cvtpk(float lo, float hi) {
  unsigned r;
  asm("v_cvt_pk_bf16_f32 %0, %1, %2" : "=v"(r) : "v"(lo), "v"(hi));
  return r;
}

// ---- pre-pass 1: K fp32 -> bf16, 32x32x16 A-fragment order ----
// KS[bh][ch][br][dc][hi][m][j] = K[bh][ch*32+m][br*32+dc*16+hi*8+j]
__global__ __launch_bounds__(256)
void kpack(const float* __restrict__ K, __bf16* __restrict__ KS) {
  const int bh = blockIdx.x >> 6, ch = blockIdx.x & 63;
  const int t = threadIdx.x;
  const int br = t >> 7, dc = (t >> 6) & 1, hi = (t >> 5) & 1, m = t & 31;
  const float* src = K + ((size_t)bh * 2048 + ch * 32 + m) * 64 + br * 32 + dc * 16 + hi * 8;
  float4 f0 = *(const float4*)src;
  float4 f1 = *(const float4*)(src + 4);
  bf16x8 v;
  v[0] = (__bf16)f0.x; v[1] = (__bf16)f0.y; v[2] = (__bf16)f0.z; v[3] = (__bf16)f0.w;
  v[4] = (__bf16)f1.x; v[5] = (__bf16)f1.y; v[6] = (__bf16)f1.z; v[7] = (__bf16)f1.w;
  *(bf16x8*)(KS + (size_t)bh * 131072 + ch * 2048 + t * 8) = v;   // coalesced
}

// ---- pre-pass 2: V fp32 [bh][s][64] -> V^T bf16, 32x32x16 A-frag order ----
// VS[bh][ch][dh][kc][hi][m][j] = V[bh][ch*32+kc*16+hi*8+j][dh*32+m]
__global__ __launch_bounds__(256)
void vpack(const float* __restrict__ V, __bf16* __restrict__ VS) {
  __shared__ float tile[64][65];
  const int bh = blockIdx.x >> 5;
  const int s0 = (blockIdx.x & 31) * 64;
  const int t = threadIdx.x;
  const float* Vb = V + (size_t)bh * 2048 * 64;
#pragma unroll
  for (int i = 0; i < 4; ++i) {
    const int r = i * 16 + (t >> 4);
    const int c4 = (t & 15) * 4;
    float4 v = *(const float4*)(Vb + (s0 + r) * 64 + c4);
    tile[r][c4] = v.x; tile[r][c4 + 1] = v.y;
    tile[r][c4 + 2] = v.z; tile[r][c4 + 3] = v.w;
  }
  __syncthreads();
  const int dh = t >> 7, kc = (t >> 6) & 1, hi = (t >> 5) & 1, m = t & 31;
#pragma unroll
  for (int hh = 0; hh < 2; ++hh) {
    const int ch = (blockIdx.x & 31) * 2 + hh;
    bf16x8 v;
#pragma unroll
    for (int j = 0; j < 8; ++j) v[j] = (__bf16)tile[hh * 32 + kc * 16 + hi * 8 + j][dh * 32 + m];
    *(bf16x8*)(VS + (size_t)bh * 131072 + ch * 2048 + t * 8) = v;
  }
}

// ---- main: 32x32 swapped-operand flash diff-attention, LDS P round-trip ----
// R12 vs R11 (failed): the in-register permlane P^T redistribution is replaced
// by the R5/R7/R10-PROVEN LDS pattern (uint2-typed array, one sched_barrier
// between writes and reads, trailing sched_barrier). Everything else kept:
// 4 QK + 8 PV 32x32x16 MFMAs/step, packed 1KB K/V wave-loads, crow epilogue.
// P entry e of row q covers kv 4e..4e+3; lane (q,hi) writes entries
// {hi, 2+hi, 4+hi, 6+hi}; reads entries {2hi,2hi+1} (bp0) {4+2hi,5+2hi} (bp1).
__global__ __launch_bounds__(256, 2)
void diffattn(const float* __restrict__ Q, const __bf16* __restrict__ KS,
              const __bf16* __restrict__ VS, const float* __restrict__ LP,
              float* __restrict__ OUT) {
  constexpr int S = 2048, D = 64;
  constexpr float QSCALE = 0.17677669529663687f * 1.4426950408889634f;

  __shared__ __align__(16) uint2 Pw[4][2][32][10];   // [w][br][q][kv-entry] 20480B

  const int raw = blockIdx.x;
  const int wg  = (raw & 7) * 64 + (raw >> 3);   // XCD swizzle (512 % 8 == 0)
  const int bh  = wg >> 4;
  const int qb  = wg & 15;
  const float lam = LP[bh & 15];

  const int tid  = threadIdx.x;
  const int w    = tid >> 6;
  const int lane = tid & 63;
  const int q    = lane & 31;    // q column owned by this lane
  const int hi   = lane >> 5;    // fragment half-select
  const int q0   = qb * 128 + w * 32;            // 32 q rows per wave

  const float*  Qb    = Q  + (size_t)bh * S * D;
  const __bf16* Kbase = KS + (size_t)bh * 131072 + lane * 8;
  const __bf16* Vbase = VS + (size_t)bh * 131072 + lane * 8;

  // Q B-fragments: bq[br][dc], element (hi,j) <-> d = br*32+dc*16+hi*8+j
  bf16x8 bq[2][2];
#pragma unroll
  for (int br = 0; br < 2; ++br)
#pragma unroll
    for (int dc = 0; dc < 2; ++dc) {
      const float* p = Qb + (size_t)(q0 + q) * D + br * 32 + dc * 16 + hi * 8;
      float4 f0 = *(const float4*)p;
      float4 f1 = *(const float4*)(p + 4);
      bf16x8 v;
      v[0] = (__bf16)(f0.x * QSCALE); v[1] = (__bf16)(f0.y * QSCALE);
      v[2] = (__bf16)(f0.z * QSCALE); v[3] = (__bf16)(f0.w * QSCALE);
      v[4] = (__bf16)(f1.x * QSCALE); v[5] = (__bf16)(f1.y * QSCALE);
      v[6] = (__bf16)(f1.z * QSCALE); v[7] = (__bf16)(f1.w * QSCALE);
      bq[br][dc] = v;
    }

  f32x16 acc[2][2] = {};    // [br][dhalf]
  float rsum[2] = {0.f, 0.f};

#define LOADK(ak, ch) do {                                             \
    const __bf16* _p = Kbase + (size_t)(ch) * 2048;                    \
    ak[0][0] = *(const bf16x8*)_p;                                     \
    ak[0][1] = *(const bf16x8*)(_p + 512);                             \
    ak[1][0] = *(const bf16x8*)(_p + 1024);                            \
    ak[1][1] = *(const bf16x8*)(_p + 1536);                            \
  } while (0)

#define LOADV(av, ch) do {                                             \
    const __bf16* _p = Vbase + (size_t)(ch) * 2048;                    \
    av[0][0] = *(const bf16x8*)_p;                                     \
    av[0][1] = *(const bf16x8*)(_p + 512);                             \
    av[1][0] = *(const bf16x8*)(_p + 1024);                            \
    av[1][1] = *(const bf16x8*)(_p + 1536);                            \
  } while (0)

#define STEP(kc_, kn_, vc_, vn_, ch) do {                                 \
    LOADK(kn_, ((ch) + 1) & 63);                                          \
    LOADV(vn_, ((ch) + 1) & 63);                                          \
    /* phase A: QK chain + exp2 + pack + DS-write, both branches */       \
    _Pragma("unroll")                                                     \
    for (int br = 0; br < 2; ++br) {                                      \
      f32x16 z = {};                                                      \
      f32x16 s = mfma32(kc_[br][1], bq[br][1],                            \
                        mfma32(kc_[br][0], bq[br][0], z));                \
      float p[16];                                                        \
      _Pragma("unroll")                                                   \
      for (int r = 0; r < 16; ++r) p[r] = __builtin_amdgcn_exp2f(s[r]);   \
      rsum[br] += ((p[0]+p[1])+(p[2]+p[3])) + ((p[4]+p[5])+(p[6]+p[7]))   \
                + ((p[8]+p[9])+(p[10]+p[11])) + ((p[12]+p[13])+(p[14]+p[15])); \
      unsigned u0 = cvtpk(p[0], p[1]),   u1 = cvtpk(p[2], p[3]);          \
      unsigned u2 = cvtpk(p[4], p[5]),   u3 = cvtpk(p[6], p[7]);          \
      unsigned u4 = cvtpk(p[8], p[9]),   u5 = cvtpk(p[10], p[11]);        \
      unsigned u6 = cvtpk(p[12], p[13]), u7 = cvtpk(p[14], p[15]);        \
      Pw[w][br][q][hi]     = make_uint2(u0, u1);   /* kv 4hi..4hi+3   */  \
      Pw[w][br][q][2 + hi] = make_uint2(u2, u3);   /* kv 8+4hi..      */  \
      Pw[w][br][q][4 + hi] = make_uint2(u4, u5);   /* kv 16+4hi..     */  \
      Pw[w][br][q][6 + hi] = make_uint2(u6, u7);   /* kv 24+4hi..     */  \
    }                                                                     \
    __builtin_amdgcn_sched_barrier(0);  /* writes before reads */         \
    /* phase B: read B-frags + PV, both branches */                       \
    _Pragma("unroll")                                                     \
    for (int br = 0; br < 2; ++br) {                                      \
      uint2 a0 = Pw[w][br][q][2 * hi];         /* kv 8hi..8hi+3   */      \
      uint2 a1 = Pw[w][br][q][2 * hi + 1];     /* kv 8hi+4..8hi+7 */      \
      uint2 b0 = Pw[w][br][q][4 + 2 * hi];     /* kv 16+8hi..     */      \
      uint2 b1 = Pw[w][br][q][5 + 2 * hi];                                \
      bf16x8 bp0 = __builtin_bit_cast(bf16x8, make_uint4(a0.x, a0.y, a1.x, a1.y)); \
      bf16x8 bp1 = __builtin_bit_cast(bf16x8, make_uint4(b0.x, b0.y, b1.x, b1.y)); \
      _Pragma("unroll")                                                   \
      for (int dh = 0; dh < 2; ++dh) {                                    \
        acc[br][dh] = mfma32(vc_[dh][0], bp0, acc[br][dh]);               \
        acc[br][dh] = mfma32(vc_[dh][1], bp1, acc[br][dh]);               \
      }                                                                   \
    }                                                                     \
    __builtin_amdgcn_sched_barrier(0);  /* reads before next step writes */ \
  } while (0)

  bf16x8 k0[2][2], k1[2][2], v0[2][2], v1[2][2];
  LOADK(k0, 0);
  LOADV(v0, 0);

#pragma unroll 1
  for (int ch = 0; ch < 64; ch += 2) {
    STEP(k0, k1, v0, v1, ch);
    STEP(k1, k0, v1, v0, ch + 1);
  }
#undef STEP
#undef LOADV
#undef LOADK

  // ---- epilogue: denominators, combine, LayerNorm, store ----
  const float rs1 = rsum[0] + __shfl_xor(rsum[0], 32);
  const float rs2 = rsum[1] + __shfl_xor(rsum[1], 32);
  const float inv1 = 1.0f / rs1;
  const float inv2 = lam / rs2;

  float xv[2][16];
  float sum = 0.f, sq = 0.f;
#pragma unroll
  for (int dh = 0; dh < 2; ++dh)
#pragma unroll
    for (int r = 0; r < 16; ++r) {
      float x = acc[0][dh][r] * inv1 - acc[1][dh][r] * inv2;
      xv[dh][r] = x;
      sum += x; sq += x * x;
    }
  // partner lane (l^32) holds the other 32 d-values of the same q row
  sum += __shfl_xor(sum, 32);
  sq  += __shfl_xor(sq, 32);
  const float mean = sum * (1.0f / 64.0f);
  const float var  = sq * (1.0f / 64.0f) - mean * mean;
  const float rstd = rsqrtf(var + 1e-5f) * 0.2f;   // * (1 - LAMBDA_INIT)

  float* op = OUT + (size_t)bh * S * D + (size_t)(q0 + q) * D;
#pragma unroll
  for (int dh = 0; dh < 2; ++dh)
#pragma unroll
    for (int qd = 0; qd < 4; ++qd) {
      float4 o;
      o.x = (xv[dh][4 * qd + 0] - mean) * rstd;
      o.y = (xv[dh][4 * qd + 1] - mean) * rstd;
      o.z = (xv[dh][4 * qd + 2] - mean) * rstd;
      o.w = (xv[dh][4 * qd + 3] - mean) * rstd;
      *(float4*)(op + 32 * dh + 8 * qd + 4 * hi) = o;  // d = (r&3)+8(r>>2)+4hi+32dh
    }
}

extern "C" void kernel_launch(void* const* d_in, const int* in_sizes, int n_in,
                              void* d_out, int out_size, void* d_ws, size_t ws_size,
                              hipStream_t stream) {
  (void)in_sizes; (void)n_in; (void)out_size; (void)ws_size;
  const float* q  = (const float*)d_in[0];
  const float* k  = (const float*)d_in[1];
  const float* v  = (const float*)d_in[2];
  const float* lp = (const float*)d_in[3];
  float* out = (float*)d_out;

  __bf16* ks = (__bf16*)d_ws;                              // 8 MiB
  __bf16* vs = (__bf16*)((char*)d_ws + (8u << 20));        // 8 MiB

  kpack<<<dim3(2048), dim3(256), 0, stream>>>(k, ks);
  vpack<<<dim3(1024), dim3(256), 0, stream>>>(v, vs);
  diffattn<<<dim3(512), dim3(256), 0, stream>>>(q, ks, vs, lp, out);
}